// Round 1
// 1274.358 us; speedup vs baseline: 1.0118x; 1.0118x over previous
//
#include <hip/hip_runtime.h>
#include <cmath>

#define B_ 32
#define S_ 512
#define NF_ 124
#define SD_ 204
#define D_ 512
#define FF_ 2048
#define H_ 8
#define L_ 4
#define T_ 513            // S+1
#define TB_ 16416         // T_*B_
#define SB_ 16384         // S_*B_
#define PE_ROWS 1024      // timesteps < 1000

typedef unsigned short u16;
typedef __attribute__((ext_vector_type(8))) short bf16x8;   // 8 bf16 in 4 VGPRs
typedef __attribute__((ext_vector_type(4))) float f32x4;

__device__ __forceinline__ u16 f2bf(float f) {
  unsigned int u = __float_as_uint(f);
  unsigned int r = u + 0x7fff + ((u >> 16) & 1);  // RNE
  return (u16)(r >> 16);
}
__device__ __forceinline__ float bf2f(u16 x) {
  return __uint_as_float((unsigned int)x << 16);
}

// XCD-aware tile swizzle: block lin -> tile such that XCD k (= lin % 8) owns a
// contiguous row-major run of tiles (A-strips stay in one XCD's L2).
// Exact bijection for any nb.
__device__ __forceinline__ int xcd_tile(int lin, int nb) {
  int xcd = lin & 7, j = lin >> 3;
  int base = nb >> 3, rem = nb & 7;
  int start = xcd * base + (xcd < rem ? xcd : rem);
  return start + j;
}

// ---------------------------------------------------------------------------
// Positional encoding table
// ---------------------------------------------------------------------------
__global__ void pe_kernel(float* __restrict__ pe) {
  int p = blockIdx.x;
  int i = threadIdx.x;  // pair index 0..255
  float div = expf(-(float)(2 * i) * (9.210340371976184f / 512.0f));
  float ang = (float)p * div;
  pe[p * 512 + 2 * i]     = sinf(ang);
  pe[p * 512 + 2 * i + 1] = cosf(ang);
}

// ---------------------------------------------------------------------------
// (B,S,C) fp32 -> (S,B,Cpad) bf16, zero-padded in C
// ---------------------------------------------------------------------------
__global__ void transpose_sb_bf(const float* __restrict__ in, u16* __restrict__ out,
                                int C, int Cpad, int total) {
  int idx = blockIdx.x * 256 + threadIdx.x;
  if (idx >= total) return;
  int c  = idx % Cpad;
  int sb = idx / Cpad;
  int b  = sb & (B_ - 1);
  int s  = sb >> 5;
  out[idx] = (c < C) ? f2bf(in[((size_t)b * S_ + s) * C + c]) : (u16)0;
}

// ---------------------------------------------------------------------------
// Batched weight convert+transpose: W[l][K][N] fp32 -> Wt[l][N][K] bf16.
// ---------------------------------------------------------------------------
__global__ __launch_bounds__(256) void wtrans_kernel(const float* __restrict__ W,
                                                     u16* __restrict__ Wt,
                                                     int K, int N,
                                                     long in_stride, long out_stride) {
  __shared__ float t[32][33];
  int l = blockIdx.z;
  W  += (size_t)l * in_stride;
  Wt += (size_t)l * out_stride;
  int n0 = blockIdx.x * 32, k0 = blockIdx.y * 32;
  int r = threadIdx.x >> 3;
  int c4 = (threadIdx.x & 7) * 4;
  float4 v = *(const float4*)(W + (size_t)(k0 + r) * N + n0 + c4);
  t[r][c4 + 0] = v.x; t[r][c4 + 1] = v.y; t[r][c4 + 2] = v.z; t[r][c4 + 3] = v.w;
  __syncthreads();
  u16* dst = Wt + (size_t)(n0 + r) * K + k0 + c4;
  for (int i = 0; i < 4; i++) dst[i] = f2bf(t[c4 + i][r]);
}

// ---------------------------------------------------------------------------
// Padded weight convert+transpose: W[K][N] fp32 -> Wt[N][Kpad] bf16, zero pad.
// ---------------------------------------------------------------------------
__global__ __launch_bounds__(256) void wtrans_pad_kernel(const float* __restrict__ W,
                                                         u16* __restrict__ Wt,
                                                         int K, int Kpad, int N) {
  __shared__ float t[32][33];
  int n0 = blockIdx.x * 32, k0 = blockIdx.y * 32;
  int r = threadIdx.x >> 3;
  int c4 = (threadIdx.x & 7) * 4;
  float4 v = make_float4(0.f, 0.f, 0.f, 0.f);
  if (k0 + r < K) v = *(const float4*)(W + (size_t)(k0 + r) * N + n0 + c4);
  t[r][c4 + 0] = v.x; t[r][c4 + 1] = v.y; t[r][c4 + 2] = v.z; t[r][c4 + 3] = v.w;
  __syncthreads();
  u16* dst = Wt + (size_t)(n0 + r) * Kpad + k0 + c4;
  for (int i = 0; i < 4; i++) dst[i] = f2bf(t[c4 + i][r]);
}

// ---------------------------------------------------------------------------
// Fused head weights: head_t[128][512] bf16 (pose cols 0..24 from h[:,:64],
// expr cols 24..124 from h[:,64:512]), head_b[128] f32.
// ---------------------------------------------------------------------------
__global__ void head_prep_kernel(const float* __restrict__ Wp, const float* __restrict__ bp,
                                 const float* __restrict__ We, const float* __restrict__ be,
                                 u16* __restrict__ head_t, float* __restrict__ head_b) {
  int idx = blockIdx.x * 256 + threadIdx.x;   // 128*512
  int n = idx >> 9, k = idx & 511;
  float v = 0.f;
  if (n < 24) { if (k < 64) v = Wp[k * 24 + n]; }
  else if (n < 124) { if (k >= 64) v = We[(size_t)(k - 64) * 100 + (n - 24)]; }
  head_t[idx] = f2bf(v);
  if (idx < 128) head_b[idx] = (idx < 24) ? bp[idx] : ((idx < 124) ? be[idx - 24] : 0.f);
}

// ---------------------------------------------------------------------------
// Gather pe rows for timesteps -> bf16 A[32][512]
// ---------------------------------------------------------------------------
__global__ void ts_gather_kernel(const int* __restrict__ tsteps,
                                 const float* __restrict__ pe,
                                 u16* __restrict__ A) {
  int idx = blockIdx.x * 256 + threadIdx.x;   // 32*512
  int b = idx >> 9, k = idx & 511;
  A[idx] = f2bf(pe[(size_t)tsteps[b] * 512 + k]);
}

// ---------------------------------------------------------------------------
// Templated bf16 MFMA GEMM, 512 threads / 8 waves, XCD-swizzled tiles.
// C[M,N] = A[M,K] @ Bt[N,K]^T + bias. BMxBN tile, BK=64 (two 32-panels).
// flags: 1 = exact GELU; 2 = SiLU; 4 = head mode (fp32 out, row remap, n<124).
// Default epilogue: bf16 via LDS-bounce coalesced stores. K%64==0, N%BN==0.
// ---------------------------------------------------------------------------
template<int BM, int BN, int WM, int WN>
__global__ __launch_bounds__(512) void gemm_bf16_t(
    const u16* __restrict__ A, const u16* __restrict__ Bt,
    const float* __restrict__ bias,
    u16* __restrict__ Cb, float* __restrict__ Cf,
    int M, int N, int K, int flags)
{
  constexpr int MT = WM / 16, NT = WN / 16;
  constexpr int ACH = BM * 8;              // A 16B-chunks per K-iter
  constexpr int TCH = (BM + BN) * 8;
  constexpr int NC  = TCH / 512;
  constexpr int WROWS = BM / WM;
  __shared__ u16 sm[(BM + BN) * 64];
  int tid = threadIdx.x;
  // XCD-aware tile mapping: all N-tiles of one A-strip land on the same XCD
  int nx = gridDim.x;
  int lin = blockIdx.y * nx + blockIdx.x;
  int tile = xcd_tile(lin, nx * gridDim.y);
  int m0 = (tile / nx) * BM, n0 = (tile % nx) * BN;
  int wave = tid >> 6, lane = tid & 63;
  int wm = (wave % WROWS) * WM, wn = (wave / WROWS) * WN;
  int lm = lane & 15, kq = lane >> 4;

  f32x4 acc[MT][NT];
#pragma unroll
  for (int i = 0; i < MT; i++)
#pragma unroll
    for (int j = 0; j < NT; j++) acc[i][j] = (f32x4){0.f, 0.f, 0.f, 0.f};

  const u16* gp[NC];
  u16* lp[NC];
#pragma unroll
  for (int i = 0; i < NC; i++) {
    int c = tid + i * 512;
    if (c < ACH) {
      int p = c / (BM * 4), cp = c % (BM * 4);
      int r = cp >> 2, kk = p * 32 + (cp & 3) * 8;
      int row = m0 + r; if (row > M - 1) row = M - 1;
      gp[i] = A + (size_t)row * K + kk;
    } else {
      int cb = c - ACH;
      int p = cb / (BN * 4), cp = cb % (BN * 4);
      int r = cp >> 2, kk = p * 32 + (cp & 3) * 8;
      int row = n0 + r; if (row > N - 1) row = N - 1;
      gp[i] = Bt + (size_t)row * K + kk;
    }
    lp[i] = sm + (size_t)c * 8;
  }

  for (int k0 = 0; k0 < K; k0 += 64) {
#pragma unroll
    for (int i = 0; i < NC; i++)
      __builtin_amdgcn_global_load_lds(
          (const __attribute__((address_space(1))) void*)(gp[i] + k0),
          (__attribute__((address_space(3))) void*)lp[i], 16, 0, 0);
    __syncthreads();
#pragma unroll
    for (int st = 0; st < 2; st++) {
      bf16x8 af[MT], bg[NT];
#pragma unroll
      for (int i = 0; i < MT; i++)
        af[i] = *(const bf16x8*)&sm[st * BM * 32 + (wm + i * 16 + lm) * 32 + kq * 8];
#pragma unroll
      for (int j = 0; j < NT; j++)
        bg[j] = *(const bf16x8*)&sm[BM * 64 + st * BN * 32 + (wn + j * 16 + lm) * 32 + kq * 8];
#pragma unroll
      for (int i = 0; i < MT; i++)
#pragma unroll
        for (int j = 0; j < NT; j++)
          acc[i][j] = __builtin_amdgcn_mfma_f32_16x16x32_bf16(af[i], bg[j], acc[i][j], 0, 0, 0);
    }
    __syncthreads();
  }

  if (flags & 4) {
    // head mode: fp32 out[b][s][0..124), rows gm=(s*B+b) remapped
#pragma unroll
    for (int j = 0; j < NT; j++) {
      int gn = n0 + wn + j * 16 + lm;
      float bv = bias[gn];
#pragma unroll
      for (int i = 0; i < MT; i++) {
        int gm = m0 + wm + i * 16 + kq * 4;
#pragma unroll
        for (int r = 0; r < 4; r++) {
          if (gm + r < M && gn < 124) {
            int bb = (gm + r) & (B_ - 1), ss = (gm + r) >> 5;
            Cf[((size_t)bb * S_ + ss) * 124 + gn] = acc[i][j][r] + bv;
          }
        }
      }
    }
    return;
  }

  // bf16 epilogue: bias(+act), bounce through sm[BM][BN] for coalesced stores
#pragma unroll
  for (int j = 0; j < NT; j++) {
    int cn = wn + j * 16 + lm;
    float bv = bias[n0 + cn];
#pragma unroll
    for (int i = 0; i < MT; i++) {
      int rm = wm + i * 16 + kq * 4;
#pragma unroll
      for (int r = 0; r < 4; r++) {
        float v = acc[i][j][r] + bv;
        if (flags & 1) v = 0.5f * v * (1.0f + erff(v * 0.70710678118654752f));
        if (flags & 2) v = v / (1.0f + expf(-v));
        sm[(rm + r) * BN + cn] = f2bf(v);
      }
    }
  }
  __syncthreads();
  constexpr int SP = BM * BN / 4096;
#pragma unroll
  for (int pass = 0; pass < SP; pass++) {
    int e = pass * 4096 + tid * 8;
    int r = e / BN, cc = e % BN;
    int gm = m0 + r;
    if (gm < M)
      *(bf16x8*)(Cb + (size_t)gm * N + n0 + cc) = *(const bf16x8*)&sm[r * BN + cc];
  }
}

// ---------------------------------------------------------------------------
// wave-per-row reduction helper: sum across 64 lanes
// ---------------------------------------------------------------------------
__device__ __forceinline__ float wave_sum(float v) {
#pragma unroll
  for (int off = 1; off < 64; off <<= 1) v += __shfl_xor(v, off, 64);
  return v;
}

// ---------------------------------------------------------------------------
// LN + leaky_relu on bf16 lmk/xi rows -> concat row of 1024 bf16.
// One wave per (row, part); block = 4 waves.
// ---------------------------------------------------------------------------
__global__ __launch_bounds__(256) void ln_leaky_concat_kernel(
    const u16* __restrict__ lmk, const u16* __restrict__ xi,
    const float* __restrict__ gl, const float* __restrict__ bl,
    const float* __restrict__ gx, const float* __restrict__ bx,
    u16* __restrict__ cat)
{
  int wave = threadIdx.x >> 6, lane = threadIdx.x & 63;
  int g = blockIdx.x * 4 + wave;        // 0..32767
  int r = g >> 1, part = g & 1;
  const u16* src = (part ? xi : lmk) + (size_t)r * 512 + lane * 8;
  const float* gg = (part ? gx : gl) + lane * 8;
  const float* bb = (part ? bx : bl) + lane * 8;
  bf16x8 hv = *(const bf16x8*)src;
  float v[8];
#pragma unroll
  for (int i = 0; i < 8; i++) v[i] = bf2f(((const u16*)&hv)[i]);
  float s = 0.f;
#pragma unroll
  for (int i = 0; i < 8; i++) s += v[i];
  float mean = wave_sum(s) * (1.0f / 512.0f);
  float s2 = 0.f;
#pragma unroll
  for (int i = 0; i < 8; i++) { v[i] -= mean; s2 += v[i] * v[i]; }
  float rs = rsqrtf(wave_sum(s2) * (1.0f / 512.0f) + 1e-5f);
  u16 ov[8];
#pragma unroll
  for (int i = 0; i < 8; i++) {
    float y = v[i] * rs * gg[i] + bb[i];
    y = (y >= 0.f) ? y : 0.2f * y;
    ov[i] = f2bf(y);
  }
  *(bf16x8*)(cat + (size_t)r * 1024 + part * 512 + lane * 8) = *(const bf16x8*)ov;
}

// ---------------------------------------------------------------------------
// h_bf = LN(h_bf + src_bf): one wave per row, block = 4 waves.
// ---------------------------------------------------------------------------
__global__ __launch_bounds__(256) void add_ln_kernel(
    u16* __restrict__ h_bf, const u16* __restrict__ src,
    const float* __restrict__ g, const float* __restrict__ be)
{
  int wave = threadIdx.x >> 6, lane = threadIdx.x & 63;
  int r = blockIdx.x * 4 + wave;
  size_t base = (size_t)r * 512 + lane * 8;
  bf16x8 hv = *(const bf16x8*)&h_bf[base];
  bf16x8 sv = *(const bf16x8*)&src[base];
  float v[8];
#pragma unroll
  for (int i = 0; i < 8; i++)
    v[i] = bf2f(((const u16*)&hv)[i]) + bf2f(((const u16*)&sv)[i]);
  float s = 0.f;
#pragma unroll
  for (int i = 0; i < 8; i++) s += v[i];
  float mean = wave_sum(s) * (1.0f / 512.0f);
  float s2 = 0.f;
#pragma unroll
  for (int i = 0; i < 8; i++) { v[i] -= mean; s2 += v[i] * v[i]; }
  float rs = rsqrtf(wave_sum(s2) * (1.0f / 512.0f) + 1e-5f);
  const float* gg = g + lane * 8;
  const float* bb = be + lane * 8;
  u16 ov[8];
#pragma unroll
  for (int i = 0; i < 8; i++) ov[i] = f2bf(v[i] * rs * gg[i] + bb[i]);
  *(bf16x8*)&h_bf[base] = *(const bf16x8*)ov;
}

// ---------------------------------------------------------------------------
// h_bf[t,b,:] += pe[t,:]  (8 elems/thread)
// ---------------------------------------------------------------------------
__global__ void add_pe_kernel(u16* __restrict__ h_bf, const float* __restrict__ pe) {
  int idx = blockIdx.x * 256 + threadIdx.x;   // grid = TB_*512/8/256 exactly
  int e = idx * 8;
  int j = e & 511;
  int t = (e >> 9) / B_;
  bf16x8 hv = *(const bf16x8*)&h_bf[e];
  const float* pv = &pe[(size_t)t * 512 + j];
  u16 ov[8];
#pragma unroll
  for (int i = 0; i < 8; i++) ov[i] = f2bf(bf2f(((const u16*)&hv)[i]) + pv[i]);
  *(bf16x8*)&h_bf[e] = *(const bf16x8*)ov;
}

// ---------------------------------------------------------------------------
// MFMA flash attention v3 + XCD swizzle: 512 threads / 8 waves, one 16-row
// q-tile per wave. All 5 q-blocks of one (b,h) land on the same XCD so KV is
// fetched once into that XCD's L2. Maxless softmax. K [s][dh] stride 72,
// V transposed [dh][s], P via wave-local LDS (C->A layout), bf16.
// ---------------------------------------------------------------------------
__global__ __launch_bounds__(512) void attn_kernel(const u16* __restrict__ qkv,
                                                   u16* __restrict__ o)
{
  __shared__ u16 Ks[64 * 72];    //  9.2 KB
  __shared__ u16 Vt[64 * 72];    //  9.2 KB
  __shared__ u16 Ps[128 * 72];   // 18.4 KB (8 waves x 16 rows)

  // XCD swizzle over grid (5, 256): nb = 1280, divisible by 8
  int lin = blockIdx.y * 5 + blockIdx.x;
  int tile = (lin & 7) * 160 + (lin >> 3);
  int bh = tile / 5, qp = tile % 5;
  int b  = bh >> 3;
  int hh = bh & 7;
  int tid  = threadIdx.x;
  int wave = tid >> 6, lane = tid & 63;
  int lm = lane & 15, quad = lane >> 4;
  int wm = wave * 16;           // wave's q-rows [wm, wm+16) within block
  int t0 = qp * 128;

  // Q fragments (A-layout), loaded once
  bf16x8 qf0, qf1;
  {
    int t = t0 + wm + lm; if (t > T_ - 1) t = T_ - 1;
    const u16* qp_ = qkv + ((size_t)(t * B_ + b)) * 1536 + hh * 64;
    qf0 = *(const bf16x8*)(qp_ + quad * 8);
    qf1 = *(const bf16x8*)(qp_ + 32 + quad * 8);
  }

  f32x4 o_acc[4];
  float lsum[4] = {0.f, 0.f, 0.f, 0.f};
#pragma unroll
  for (int dt = 0; dt < 4; dt++) o_acc[dt] = (f32x4){0.f, 0.f, 0.f, 0.f};

  const float cs = 0.125f * 1.4426950408889634f;  // scale * log2(e)

  for (int s0 = 0; s0 < T_; s0 += 64) {
    __syncthreads();
    // stage K [s][dh]: 512 chunks of 16B, one per thread
    {
      int sr = tid >> 3, db = (tid & 7) * 8;
      int s = s0 + sr; if (s > T_ - 1) s = T_ - 1;
      *(bf16x8*)&Ks[sr * 72 + db] =
          *(const bf16x8*)(qkv + ((size_t)(s * B_ + b)) * 1536 + 512 + hh * 64 + db);
    }
    // stage V transposed [dh][s]: 512 chunks, one per thread
    {
      int sr = tid & 63, db = (tid >> 6) * 8;
      int s = s0 + sr; if (s > T_ - 1) s = T_ - 1;
      bf16x8 vv = *(const bf16x8*)(qkv + ((size_t)(s * B_ + b)) * 1536 + 1024 + hh * 64 + db);
      const u16* pv = (const u16*)&vv;
#pragma unroll
      for (int i = 0; i < 8; i++) Vt[(db + i) * 72 + sr] = pv[i];
    }
    __syncthreads();

    // S = Q K^T
    f32x4 sacc[4];
#pragma unroll
    for (int st = 0; st < 4; st++) {
      sacc[st] = (f32x4){0.f, 0.f, 0.f, 0.f};
      bf16x8 k0 = *(const bf16x8*)&Ks[(st * 16 + lm) * 72 + quad * 8];
      bf16x8 k1 = *(const bf16x8*)&Ks[(st * 16 + lm) * 72 + 32 + quad * 8];
      sacc[st] = __builtin_amdgcn_mfma_f32_16x16x32_bf16(qf0, k0, sacc[st], 0, 0, 0);
      sacc[st] = __builtin_amdgcn_mfma_f32_16x16x32_bf16(qf1, k1, sacc[st], 0, 0, 0);
    }
    // maxless softmax: p = exp2(s*cs); masked keys -> 0
#pragma unroll
    for (int st = 0; st < 4; st++) {
      bool bad = (s0 + st * 16 + lm) >= T_;
#pragma unroll
      for (int r = 0; r < 4; r++) {
        float v = bad ? -10000.f : sacc[st][r] * cs;
        float p = exp2f(v);
        sacc[st][r] = p;
        lsum[r] += p;
      }
    }
    // P: C-layout -> LDS bf16 (wave-local rows)
#pragma unroll
    for (int st = 0; st < 4; st++)
#pragma unroll
      for (int r = 0; r < 4; r++)
        Ps[(wm + quad * 4 + r) * 72 + st * 16 + lm] = f2bf(sacc[st][r]);
    // O += P V (same-wave produce/consume, no barrier)
#pragma unroll
    for (int ks = 0; ks < 2; ks++) {
      bf16x8 pf = *(const bf16x8*)&Ps[(wm + lm) * 72 + ks * 32 + quad * 8];
#pragma unroll
      for (int dt = 0; dt < 4; dt++) {
        bf16x8 vf = *(const bf16x8*)&Vt[(dt * 16 + lm) * 72 + ks * 32 + quad * 8];
        o_acc[dt] = __builtin_amdgcn_mfma_f32_16x16x32_bf16(pf, vf, o_acc[dt], 0, 0, 0);
      }
    }
  }

  // epilogue: quad-reduce lsum, normalize via wave-local Ps bounce, store
  float inv[4];
#pragma unroll
  for (int r = 0; r < 4; r++) {
    float s = lsum[r];
#pragma unroll
    for (int off = 1; off < 16; off <<= 1) s += __shfl_xor(s, off, 64);
    inv[r] = 1.0f / s;
  }
#pragma unroll
  for (int dt = 0; dt < 4; dt++)
#pragma unroll
    for (int r = 0; r < 4; r++)
      Ps[(wm + quad * 4 + r) * 72 + dt * 16 + lm] = f2bf(o_acc[dt][r] * inv[r]);
  {
    int rr = wm + (lane >> 2);
    int db = (lane & 3) * 16;
    int t = t0 + rr;
    if (t < T_) {
      bf16x8 a = *(const bf16x8*)&Ps[rr * 72 + db];
      bf16x8 b8 = *(const bf16x8*)&Ps[rr * 72 + db + 8];
      u16* op = o + ((size_t)(t * B_ + b)) * 512 + hh * 64 + db;
      *(bf16x8*)op = a;
      *(bf16x8*)(op + 8) = b8;
    }
  }
}

// ---------------------------------------------------------------------------
extern "C" void kernel_launch(void* const* d_in, const int* in_sizes, int n_in,
                              void* d_out, int out_size, void* d_ws, size_t ws_size,
                              hipStream_t stream) {
  const float* x       = (const float*)d_in[0];
  const int*   tsteps  = (const int*)  d_in[1];
  const float* se      = (const float*)d_in[2];
  const float* W_lmk   = (const float*)d_in[3];
  const float* b_lmk   = (const float*)d_in[4];
  const float* g_lmk   = (const float*)d_in[5];
  const float* be_lmk  = (const float*)d_in[6];
  const float* W_in    = (const float*)d_in[7];
  const float* b_in    = (const float*)d_in[8];
  const float* g_in    = (const float*)d_in[9];
  const float* be_in   = (const float*)d_in[10];
  const float* W_merge = (const float*)d_in[11];
  const float* b_merge = (const float*)d_in[12];
  const float* Wt1     = (const float*)d_in[13];
  const float* bt1     = (const float*)d_in[14];
  const float* Wt2     = (const float*)d_in[15];
  const float* bt2     = (const float*)d_in[16];
  const float* in_proj_w  = (const float*)d_in[17];
  const float* in_proj_b  = (const float*)d_in[18];
  const float* out_proj_w = (const float*)d_in[19];
  const float* out_proj_b = (const float*)d_in[20];
  const float* ln1_g   = (const float*)d_in[21];
  const float* ln1_b   = (const float*)d_in[22];
  const float* ln2_g   = (const float*)d_in[23];
  const float* ln2_b   = (const float*)d_in[24];
  const float* W_ff1   = (const float*)d_in[25];
  const float* b_ff1   = (const float*)d_in[26];
  const float* W_ff2   = (const float*)d_in[27];
  const float* b_ff2   = (const float*)d_in[28];
  const float* W_pose  = (const float*)d_in[29];
  const float* b_pose  = (const float*)d_in[30];
  const float* W_expr  = (const float*)d_in[31];
  const float* b_expr  = (const float*)d_in[32];
  float* out = (float*)d_out;

  // ---- workspace layout (~149 MB) ----
  float* pe      = (float*)d_ws;                          // 1024*512 f32
  u16*   h_bf    = (u16*)(pe + (size_t)PE_ROWS * 512);    // TB*512 bf16
  u16*   big_bf  = h_bf + (size_t)TB_ * 512;              // TB*2048 bf16
  u16*   bufO_bf = big_bf + (size_t)TB_ * 2048;           // TB*512 bf16
  u16*   bufP_bf = bufO_bf + (size_t)TB_ * 512;           // TB*512 bf16
  u16* merge_t = bufP_bf + (size_t)TB_ * 512;             // 512*1024
  u16* ip_t    = merge_t + (size_t)512 * 1024;            // L*1536*512
  u16* op_t    = ip_t    + (size_t)L_ * 1536 * 512;       // L*512*512
  u16* ff1_t   = op_t    + (size_t)L_ * 512 * 512;        // L*2048*512
  u16* ff2_t   = ff1_t   + (size_t)L_ * 2048 * 512;       // L*512*2048
  u16* lmk_t   = ff2_t   + (size_t)L_ * 512 * 2048;       // 512*256
  u16* xin_t   = lmk_t   + (size_t)512 * 256;             // 512*128
  u16* head_t  = xin_t   + (size_t)512 * 128;             // 128*512
  u16* wt1_t   = head_t  + (size_t)128 * 512;             // 512*512
  u16* wt2_t   = wt1_t   + (size_t)512 * 512;             // 512*512
  u16* ts_in   = wt2_t   + (size_t)512 * 512;             // 32*512
  u16* ts_mid  = ts_in   + (size_t)32 * 512;              // 32*512
  float* head_b = (float*)(ts_mid + (size_t)32 * 512);    // 128 f32
  // embed-phase aliases
  u16* seT_bf = bufO_bf;                                  // SB*256 bf16 (8.4<=16.8)
  u16* xT_bf  = bufP_bf;                                  // SB*128 bf16 (4.2<=16.8)
  u16* lmk_bf = big_bf;                                   // SB*512
  u16* xi_bf  = big_bf + (size_t)SB_ * 512;               // SB*512
  u16* cat_bf = big_bf + (size_t)SB_ * 1024;              // SB*1024 (fits in big)

  auto g128 = [&](const u16* A, const u16* Bt, const float* bias, u16* Cb,
                  int M, int N, int K, int flags) {
    dim3 grid(N / 128, (M + 127) / 128);
    gemm_bf16_t<128, 128, 32, 64><<<grid, 512, 0, stream>>>(A, Bt, bias, Cb, nullptr, M, N, K, flags);
  };
  auto g64 = [&](const u16* A, const u16* Bt, const float* bias, u16* Cb, float* Cf,
                 int M, int N, int K, int flags) {
    dim3 grid(N / 128, (M + 63) / 64);
    gemm_bf16_t<64, 128, 32, 32><<<grid, 512, 0, stream>>>(A, Bt, bias, Cb, Cf, M, N, K, flags);
  };

  // ---- weight prep ----
  wtrans_kernel<<<dim3(512 / 32, 1024 / 32, 1), 256, 0, stream>>>(
      W_merge, merge_t, 1024, 512, 0, 0);
  wtrans_kernel<<<dim3(1536 / 32, 512 / 32, L_), 256, 0, stream>>>(
      in_proj_w, ip_t, 512, 1536, (long)512 * 1536, (long)1536 * 512);
  wtrans_kernel<<<dim3(512 / 32, 512 / 32, L_), 256, 0, stream>>>(
      out_proj_w, op_t, 512, 512, (long)512 * 512, (long)512 * 512);
  wtrans_kernel<<<dim3(2048 / 32, 512 / 32, L_), 256, 0, stream>>>(
      W_ff1, ff1_t, 512, 2048, (long)512 * 2048, (long)2048 * 512);
  wtrans_kernel<<<dim3(512 / 32, 2048 / 32, L_), 256, 0, stream>>>(
      W_ff2, ff2_t, 2048, 512, (long)2048 * 512, (long)512 * 2048);
  wtrans_kernel<<<dim3(512 / 32, 512 / 32, 1), 256, 0, stream>>>(Wt1, wt1_t, 512, 512, 0, 0);
  wtrans_kernel<<<dim3(512 / 32, 512 / 32, 1), 256, 0, stream>>>(Wt2, wt2_t, 512, 512, 0, 0);
  wtrans_pad_kernel<<<dim3(512 / 32, 256 / 32), 256, 0, stream>>>(W_lmk, lmk_t, SD_, 256, 512);
  wtrans_pad_kernel<<<dim3(512 / 32, 128 / 32), 256, 0, stream>>>(W_in, xin_t, NF_, 128, 512);
  head_prep_kernel<<<(128 * 512) / 256, 256, 0, stream>>>(W_pose, b_pose, W_expr, b_expr,
                                                          head_t, head_b);

  // ---- embeddings ----
  pe_kernel<<<PE_ROWS, 256, 0, stream>>>(pe);
  transpose_sb_bf<<<(SB_ * 256 + 255) / 256, 256, 0, stream>>>(se, seT_bf, SD_, 256, SB_ * 256);
  transpose_sb_bf<<<(SB_ * 128 + 255) / 256, 256, 0, stream>>>(x, xT_bf, NF_, 128, SB_ * 128);
  // 128-row tiles for all SB_/TB_-sized GEMMs (measured tile ladder: 64-tall
  // tile halves per-wave MFMA density in this 2-barrier structure)
  g128(seT_bf, lmk_t, b_lmk, lmk_bf, SB_, 512, 256, 0);
  g128(xT_bf, xin_t, b_in, xi_bf, SB_, 512, 128, 0);
  ln_leaky_concat_kernel<<<SB_ * 2 / 4, 256, 0, stream>>>(lmk_bf, xi_bf, g_lmk, be_lmk,
                                                          g_in, be_in, cat_bf);
  g128(cat_bf, merge_t, b_merge, h_bf + (size_t)B_ * 512, SB_, 512, 1024, 0);
  // timestep MLP via MFMA: gather -> GEMM+silu -> GEMM (writes h rows 0..B)
  ts_gather_kernel<<<(32 * 512) / 256, 256, 0, stream>>>(tsteps, pe, ts_in);
  g64(ts_in, wt1_t, bt1, ts_mid, nullptr, 32, 512, 512, 2);
  g64(ts_mid, wt2_t, bt2, h_bf, nullptr, 32, 512, 512, 0);
  add_pe_kernel<<<TB_ * 512 / 8 / 256, 256, 0, stream>>>(h_bf, pe);

  // ---- transformer layers ----
  for (int l = 0; l < L_; l++) {
    g128(h_bf, ip_t + (size_t)l * 1536 * 512, in_proj_b + l * 1536,
         big_bf, TB_, 1536, 512, 0);
    attn_kernel<<<dim3(5, B_ * H_), 512, 0, stream>>>(big_bf, bufO_bf);
    g128(bufO_bf, op_t + (size_t)l * 512 * 512, out_proj_b + l * 512,
         bufP_bf, TB_, 512, 512, 0);
    add_ln_kernel<<<TB_ / 4, 256, 0, stream>>>(h_bf, bufP_bf, ln1_g + l * 512, ln1_b + l * 512);
    g128(h_bf, ff1_t + (size_t)l * 2048 * 512, b_ff1 + l * 2048,
         big_bf, TB_, 2048, 512, 1);
    g128(big_bf, ff2_t + (size_t)l * 512 * 2048, b_ff2 + l * 512,
         bufP_bf, TB_, 512, 2048, 0);
    add_ln_kernel<<<TB_ / 4, 256, 0, stream>>>(h_bf, bufP_bf, ln2_g + l * 512, ln2_b + l * 512);
  }

  // ---- fused output heads: one GEMM, fp32 remap epilogue ----
  g64(h_bf + (size_t)B_ * 512, head_t, head_b, nullptr, out, SB_, 128, 512, 4);
}

// Round 2
// 1250.251 us; speedup vs baseline: 1.0313x; 1.0193x over previous
//
#include <hip/hip_runtime.h>
#include <cmath>

#define B_ 32
#define S_ 512
#define NF_ 124
#define SD_ 204
#define D_ 512
#define FF_ 2048
#define H_ 8
#define L_ 4
#define T_ 513            // S+1
#define TB_ 16416         // T_*B_
#define SB_ 16384         // S_*B_
#define PE_ROWS 1024      // timesteps < 1000

typedef unsigned short u16;
typedef __attribute__((ext_vector_type(8))) short bf16x8;   // 8 bf16 in 4 VGPRs
typedef __attribute__((ext_vector_type(4))) float f32x4;

__device__ __forceinline__ u16 f2bf(float f) {
  unsigned int u = __float_as_uint(f);
  unsigned int r = u + 0x7fff + ((u >> 16) & 1);  // RNE
  return (u16)(r >> 16);
}
__device__ __forceinline__ float bf2f(u16 x) {
  return __uint_as_float((unsigned int)x << 16);
}

// XCD-aware tile swizzle: block lin -> tile such that XCD k (= lin % 8) owns a
// contiguous row-major run of tiles (A-strips stay in one XCD's L2).
// Exact bijection for any nb.
__device__ __forceinline__ int xcd_tile(int lin, int nb) {
  int xcd = lin & 7, j = lin >> 3;
  int base = nb >> 3, rem = nb & 7;
  int start = xcd * base + (xcd < rem ? xcd : rem);
  return start + j;
}

// ---------------------------------------------------------------------------
// Positional encoding table
// ---------------------------------------------------------------------------
__global__ void pe_kernel(float* __restrict__ pe) {
  int p = blockIdx.x;
  int i = threadIdx.x;  // pair index 0..255
  float div = expf(-(float)(2 * i) * (9.210340371976184f / 512.0f));
  float ang = (float)p * div;
  pe[p * 512 + 2 * i]     = sinf(ang);
  pe[p * 512 + 2 * i + 1] = cosf(ang);
}

// ---------------------------------------------------------------------------
// (B,S,C) fp32 -> (S,B,Cpad) bf16, zero-padded in C
// ---------------------------------------------------------------------------
__global__ void transpose_sb_bf(const float* __restrict__ in, u16* __restrict__ out,
                                int C, int Cpad, int total) {
  int idx = blockIdx.x * 256 + threadIdx.x;
  if (idx >= total) return;
  int c  = idx % Cpad;
  int sb = idx / Cpad;
  int b  = sb & (B_ - 1);
  int s  = sb >> 5;
  out[idx] = (c < C) ? f2bf(in[((size_t)b * S_ + s) * C + c]) : (u16)0;
}

// ---------------------------------------------------------------------------
// Batched weight convert+transpose: W[l][K][N] fp32 -> Wt[l][N][K] bf16.
// ---------------------------------------------------------------------------
__global__ __launch_bounds__(256) void wtrans_kernel(const float* __restrict__ W,
                                                     u16* __restrict__ Wt,
                                                     int K, int N,
                                                     long in_stride, long out_stride) {
  __shared__ float t[32][33];
  int l = blockIdx.z;
  W  += (size_t)l * in_stride;
  Wt += (size_t)l * out_stride;
  int n0 = blockIdx.x * 32, k0 = blockIdx.y * 32;
  int r = threadIdx.x >> 3;
  int c4 = (threadIdx.x & 7) * 4;
  float4 v = *(const float4*)(W + (size_t)(k0 + r) * N + n0 + c4);
  t[r][c4 + 0] = v.x; t[r][c4 + 1] = v.y; t[r][c4 + 2] = v.z; t[r][c4 + 3] = v.w;
  __syncthreads();
  u16* dst = Wt + (size_t)(n0 + r) * K + k0 + c4;
  for (int i = 0; i < 4; i++) dst[i] = f2bf(t[c4 + i][r]);
}

// ---------------------------------------------------------------------------
// Padded weight convert+transpose: W[K][N] fp32 -> Wt[N][Kpad] bf16, zero pad.
// ---------------------------------------------------------------------------
__global__ __launch_bounds__(256) void wtrans_pad_kernel(const float* __restrict__ W,
                                                         u16* __restrict__ Wt,
                                                         int K, int Kpad, int N) {
  __shared__ float t[32][33];
  int n0 = blockIdx.x * 32, k0 = blockIdx.y * 32;
  int r = threadIdx.x >> 3;
  int c4 = (threadIdx.x & 7) * 4;
  float4 v = make_float4(0.f, 0.f, 0.f, 0.f);
  if (k0 + r < K) v = *(const float4*)(W + (size_t)(k0 + r) * N + n0 + c4);
  t[r][c4 + 0] = v.x; t[r][c4 + 1] = v.y; t[r][c4 + 2] = v.z; t[r][c4 + 3] = v.w;
  __syncthreads();
  u16* dst = Wt + (size_t)(n0 + r) * Kpad + k0 + c4;
  for (int i = 0; i < 4; i++) dst[i] = f2bf(t[c4 + i][r]);
}

// ---------------------------------------------------------------------------
// Fused head weights: head_t[128][512] bf16 (pose cols 0..24 from h[:,:64],
// expr cols 24..124 from h[:,64:512]), head_b[128] f32.
// ---------------------------------------------------------------------------
__global__ void head_prep_kernel(const float* __restrict__ Wp, const float* __restrict__ bp,
                                 const float* __restrict__ We, const float* __restrict__ be,
                                 u16* __restrict__ head_t, float* __restrict__ head_b) {
  int idx = blockIdx.x * 256 + threadIdx.x;   // 128*512
  int n = idx >> 9, k = idx & 511;
  float v = 0.f;
  if (n < 24) { if (k < 64) v = Wp[k * 24 + n]; }
  else if (n < 124) { if (k >= 64) v = We[(size_t)(k - 64) * 100 + (n - 24)]; }
  head_t[idx] = f2bf(v);
  if (idx < 128) head_b[idx] = (idx < 24) ? bp[idx] : ((idx < 124) ? be[idx - 24] : 0.f);
}

// ---------------------------------------------------------------------------
// Gather pe rows for timesteps -> bf16 A[32][512]
// ---------------------------------------------------------------------------
__global__ void ts_gather_kernel(const int* __restrict__ tsteps,
                                 const float* __restrict__ pe,
                                 u16* __restrict__ A) {
  int idx = blockIdx.x * 256 + threadIdx.x;   // 32*512
  int b = idx >> 9, k = idx & 511;
  A[idx] = f2bf(pe[(size_t)tsteps[b] * 512 + k]);
}

// ---------------------------------------------------------------------------
// Templated bf16 MFMA GEMM, 512 threads / 8 waves, XCD-swizzled tiles.
// C[M,N] = A[M,K] @ Bt[N,K]^T + bias. BMxBN tile, BK=64 (two 32-panels).
// flags: 1 = exact GELU; 2 = SiLU; 4 = head mode (fp32 out, row remap, n<124).
// Default epilogue: bf16 via LDS-bounce coalesced stores. K%64==0, N%BN==0.
// ---------------------------------------------------------------------------
template<int BM, int BN, int WM, int WN>
__global__ __launch_bounds__(512) void gemm_bf16_t(
    const u16* __restrict__ A, const u16* __restrict__ Bt,
    const float* __restrict__ bias,
    u16* __restrict__ Cb, float* __restrict__ Cf,
    int M, int N, int K, int flags)
{
  constexpr int MT = WM / 16, NT = WN / 16;
  constexpr int ACH = BM * 8;              // A 16B-chunks per K-iter
  constexpr int TCH = (BM + BN) * 8;
  constexpr int NC  = TCH / 512;
  constexpr int WROWS = BM / WM;
  __shared__ u16 sm[(BM + BN) * 64];
  int tid = threadIdx.x;
  // XCD-aware tile mapping: all N-tiles of one A-strip land on the same XCD
  int nx = gridDim.x;
  int lin = blockIdx.y * nx + blockIdx.x;
  int tile = xcd_tile(lin, nx * gridDim.y);
  int m0 = (tile / nx) * BM, n0 = (tile % nx) * BN;
  int wave = tid >> 6, lane = tid & 63;
  int wm = (wave % WROWS) * WM, wn = (wave / WROWS) * WN;
  int lm = lane & 15, kq = lane >> 4;

  f32x4 acc[MT][NT];
#pragma unroll
  for (int i = 0; i < MT; i++)
#pragma unroll
    for (int j = 0; j < NT; j++) acc[i][j] = (f32x4){0.f, 0.f, 0.f, 0.f};

  const u16* gp[NC];
  u16* lp[NC];
#pragma unroll
  for (int i = 0; i < NC; i++) {
    int c = tid + i * 512;
    if (c < ACH) {
      int p = c / (BM * 4), cp = c % (BM * 4);
      int r = cp >> 2, kk = p * 32 + (cp & 3) * 8;
      int row = m0 + r; if (row > M - 1) row = M - 1;
      gp[i] = A + (size_t)row * K + kk;
    } else {
      int cb = c - ACH;
      int p = cb / (BN * 4), cp = cb % (BN * 4);
      int r = cp >> 2, kk = p * 32 + (cp & 3) * 8;
      int row = n0 + r; if (row > N - 1) row = N - 1;
      gp[i] = Bt + (size_t)row * K + kk;
    }
    lp[i] = sm + (size_t)c * 8;
  }

  for (int k0 = 0; k0 < K; k0 += 64) {
#pragma unroll
    for (int i = 0; i < NC; i++)
      __builtin_amdgcn_global_load_lds(
          (const __attribute__((address_space(1))) void*)(gp[i] + k0),
          (__attribute__((address_space(3))) void*)lp[i], 16, 0, 0);
    __syncthreads();
#pragma unroll
    for (int st = 0; st < 2; st++) {
      bf16x8 af[MT], bg[NT];
#pragma unroll
      for (int i = 0; i < MT; i++)
        af[i] = *(const bf16x8*)&sm[st * BM * 32 + (wm + i * 16 + lm) * 32 + kq * 8];
#pragma unroll
      for (int j = 0; j < NT; j++)
        bg[j] = *(const bf16x8*)&sm[BM * 64 + st * BN * 32 + (wn + j * 16 + lm) * 32 + kq * 8];
#pragma unroll
      for (int i = 0; i < MT; i++)
#pragma unroll
        for (int j = 0; j < NT; j++)
          acc[i][j] = __builtin_amdgcn_mfma_f32_16x16x32_bf16(af[i], bg[j], acc[i][j], 0, 0, 0);
    }
    __syncthreads();
  }

  if (flags & 4) {
    // head mode: fp32 out[b][s][0..124), rows gm=(s*B+b) remapped
#pragma unroll
    for (int j = 0; j < NT; j++) {
      int gn = n0 + wn + j * 16 + lm;
      float bv = bias[gn];
#pragma unroll
      for (int i = 0; i < MT; i++) {
        int gm = m0 + wm + i * 16 + kq * 4;
#pragma unroll
        for (int r = 0; r < 4; r++) {
          if (gm + r < M && gn < 124) {
            int bb = (gm + r) & (B_ - 1), ss = (gm + r) >> 5;
            Cf[((size_t)bb * S_ + ss) * 124 + gn] = acc[i][j][r] + bv;
          }
        }
      }
    }
    return;
  }

  // bf16 epilogue: bias(+act), bounce through sm[BM][BN] for coalesced stores
#pragma unroll
  for (int j = 0; j < NT; j++) {
    int cn = wn + j * 16 + lm;
    float bv = bias[n0 + cn];
#pragma unroll
    for (int i = 0; i < MT; i++) {
      int rm = wm + i * 16 + kq * 4;
#pragma unroll
      for (int r = 0; r < 4; r++) {
        float v = acc[i][j][r] + bv;
        if (flags & 1) v = 0.5f * v * (1.0f + erff(v * 0.70710678118654752f));
        if (flags & 2) v = v / (1.0f + expf(-v));
        sm[(rm + r) * BN + cn] = f2bf(v);
      }
    }
  }
  __syncthreads();
  constexpr int SP = BM * BN / 4096;
#pragma unroll
  for (int pass = 0; pass < SP; pass++) {
    int e = pass * 4096 + tid * 8;
    int r = e / BN, cc = e % BN;
    int gm = m0 + r;
    if (gm < M)
      *(bf16x8*)(Cb + (size_t)gm * N + n0 + cc) = *(const bf16x8*)&sm[r * BN + cc];
  }
}

// ---------------------------------------------------------------------------
// wave-per-row reduction helper: sum across 64 lanes
// ---------------------------------------------------------------------------
__device__ __forceinline__ float wave_sum(float v) {
#pragma unroll
  for (int off = 1; off < 64; off <<= 1) v += __shfl_xor(v, off, 64);
  return v;
}

// ---------------------------------------------------------------------------
// LN + leaky_relu on bf16 lmk/xi rows -> concat row of 1024 bf16.
// One wave per (row, part); block = 4 waves.
// ---------------------------------------------------------------------------
__global__ __launch_bounds__(256) void ln_leaky_concat_kernel(
    const u16* __restrict__ lmk, const u16* __restrict__ xi,
    const float* __restrict__ gl, const float* __restrict__ bl,
    const float* __restrict__ gx, const float* __restrict__ bx,
    u16* __restrict__ cat)
{
  int wave = threadIdx.x >> 6, lane = threadIdx.x & 63;
  int g = blockIdx.x * 4 + wave;        // 0..32767
  int r = g >> 1, part = g & 1;
  const u16* src = (part ? xi : lmk) + (size_t)r * 512 + lane * 8;
  const float* gg = (part ? gx : gl) + lane * 8;
  const float* bb = (part ? bx : bl) + lane * 8;
  bf16x8 hv = *(const bf16x8*)src;
  float v[8];
#pragma unroll
  for (int i = 0; i < 8; i++) v[i] = bf2f(((const u16*)&hv)[i]);
  float s = 0.f;
#pragma unroll
  for (int i = 0; i < 8; i++) s += v[i];
  float mean = wave_sum(s) * (1.0f / 512.0f);
  float s2 = 0.f;
#pragma unroll
  for (int i = 0; i < 8; i++) { v[i] -= mean; s2 += v[i] * v[i]; }
  float rs = rsqrtf(wave_sum(s2) * (1.0f / 512.0f) + 1e-5f);
  u16 ov[8];
#pragma unroll
  for (int i = 0; i < 8; i++) {
    float y = v[i] * rs * gg[i] + bb[i];
    y = (y >= 0.f) ? y : 0.2f * y;
    ov[i] = f2bf(y);
  }
  *(bf16x8*)(cat + (size_t)r * 1024 + part * 512 + lane * 8) = *(const bf16x8*)ov;
}

// ---------------------------------------------------------------------------
// h_bf = LN(h_bf + src_bf): one wave per row, block = 4 waves.
// ---------------------------------------------------------------------------
__global__ __launch_bounds__(256) void add_ln_kernel(
    u16* __restrict__ h_bf, const u16* __restrict__ src,
    const float* __restrict__ g, const float* __restrict__ be)
{
  int wave = threadIdx.x >> 6, lane = threadIdx.x & 63;
  int r = blockIdx.x * 4 + wave;
  size_t base = (size_t)r * 512 + lane * 8;
  bf16x8 hv = *(const bf16x8*)&h_bf[base];
  bf16x8 sv = *(const bf16x8*)&src[base];
  float v[8];
#pragma unroll
  for (int i = 0; i < 8; i++)
    v[i] = bf2f(((const u16*)&hv)[i]) + bf2f(((const u16*)&sv)[i]);
  float s = 0.f;
#pragma unroll
  for (int i = 0; i < 8; i++) s += v[i];
  float mean = wave_sum(s) * (1.0f / 512.0f);
  float s2 = 0.f;
#pragma unroll
  for (int i = 0; i < 8; i++) { v[i] -= mean; s2 += v[i] * v[i]; }
  float rs = rsqrtf(wave_sum(s2) * (1.0f / 512.0f) + 1e-5f);
  const float* gg = g + lane * 8;
  const float* bb = be + lane * 8;
  u16 ov[8];
#pragma unroll
  for (int i = 0; i < 8; i++) ov[i] = f2bf(v[i] * rs * gg[i] + bb[i]);
  *(bf16x8*)&h_bf[base] = *(const bf16x8*)ov;
}

// ---------------------------------------------------------------------------
// h_bf[t,b,:] += pe[t,:]  (8 elems/thread)
// ---------------------------------------------------------------------------
__global__ void add_pe_kernel(u16* __restrict__ h_bf, const float* __restrict__ pe) {
  int idx = blockIdx.x * 256 + threadIdx.x;   // grid = TB_*512/8/256 exactly
  int e = idx * 8;
  int j = e & 511;
  int t = (e >> 9) / B_;
  bf16x8 hv = *(const bf16x8*)&h_bf[e];
  const float* pv = &pe[(size_t)t * 512 + j];
  u16 ov[8];
#pragma unroll
  for (int i = 0; i < 8; i++) ov[i] = f2bf(bf2f(((const u16*)&hv)[i]) + pv[i]);
  *(bf16x8*)&h_bf[e] = *(const bf16x8*)ov;
}

// ---------------------------------------------------------------------------
// MFMA flash attention v4: swapped QK^T (mfma(K,Q) -> S^T in C-layout) so each
// lane owns 4 consecutive k-values of one q-column. P->LDS becomes
// 4x ds_write_b64 via v_cvt_pk_bf16_f32 (was 16 scalar b16 writes + 64 VALU
// f2bf, the round-1 profile's 6.7M bank conflicts + VALUBusy 55%).
// K [s][dh] stride 72, V transposed [dh][s], same-wave P produce/consume.
// lsum is one scalar per lane (column q=lm), quad-reduced once at the end.
// ---------------------------------------------------------------------------
__global__ __launch_bounds__(512) void attn_kernel(const u16* __restrict__ qkv,
                                                   u16* __restrict__ o)
{
  __shared__ u16 Ks[64 * 72];    //  9.2 KB
  __shared__ u16 Vt[64 * 72];    //  9.2 KB
  __shared__ u16 Ps[128 * 72];   // 18.4 KB (8 waves x 16 rows)

  // XCD swizzle over grid (5, 256): nb = 1280, divisible by 8
  int lin = blockIdx.y * 5 + blockIdx.x;
  int tile = (lin & 7) * 160 + (lin >> 3);
  int bh = tile / 5, qp = tile % 5;
  int b  = bh >> 3;
  int hh = bh & 7;
  int tid  = threadIdx.x;
  int wave = tid >> 6, lane = tid & 63;
  int lm = lane & 15, quad = lane >> 4;
  int wm = wave * 16;           // wave's q-rows [wm, wm+16) within block
  int t0 = qp * 128;

  // Q fragments, loaded once. Same registers serve as the mfma B-operand:
  // lane (quad,lm) holds Q[q=lm][d=quad*8+j] == B[k=quad*8+j][col=lm].
  bf16x8 qf0, qf1;
  {
    int t = t0 + wm + lm; if (t > T_ - 1) t = T_ - 1;
    const u16* qp_ = qkv + ((size_t)(t * B_ + b)) * 1536 + hh * 64;
    qf0 = *(const bf16x8*)(qp_ + quad * 8);
    qf1 = *(const bf16x8*)(qp_ + 32 + quad * 8);
  }

  f32x4 o_acc[4];
  float lsum = 0.f;
#pragma unroll
  for (int dt = 0; dt < 4; dt++) o_acc[dt] = (f32x4){0.f, 0.f, 0.f, 0.f};

  const float cs = 0.125f * 1.4426950408889634f;  // scale * log2(e)

  for (int s0 = 0; s0 < T_; s0 += 64) {
    __syncthreads();
    // stage K [s][dh]: 512 chunks of 16B, one per thread
    {
      int sr = tid >> 3, db = (tid & 7) * 8;
      int s = s0 + sr; if (s > T_ - 1) s = T_ - 1;
      *(bf16x8*)&Ks[sr * 72 + db] =
          *(const bf16x8*)(qkv + ((size_t)(s * B_ + b)) * 1536 + 512 + hh * 64 + db);
    }
    // stage V transposed [dh][s]: 512 chunks, one per thread
    {
      int sr = tid & 63, db = (tid >> 6) * 8;
      int s = s0 + sr; if (s > T_ - 1) s = T_ - 1;
      bf16x8 vv = *(const bf16x8*)(qkv + ((size_t)(s * B_ + b)) * 1536 + 1024 + hh * 64 + db);
      const u16* pv = (const u16*)&vv;
#pragma unroll
      for (int i = 0; i < 8; i++) Vt[(db + i) * 72 + sr] = pv[i];
    }
    __syncthreads();

    // S^T = K Q^T (swapped operands): lane (quad,lm) gets
    // S[k = st*16 + quad*4 + r][q = lm] — 4 consecutive k per q-column.
    f32x4 sacc[4];
#pragma unroll
    for (int st = 0; st < 4; st++) {
      sacc[st] = (f32x4){0.f, 0.f, 0.f, 0.f};
      bf16x8 k0 = *(const bf16x8*)&Ks[(st * 16 + lm) * 72 + quad * 8];
      bf16x8 k1 = *(const bf16x8*)&Ks[(st * 16 + lm) * 72 + 32 + quad * 8];
      sacc[st] = __builtin_amdgcn_mfma_f32_16x16x32_bf16(k0, qf0, sacc[st], 0, 0, 0);
      sacc[st] = __builtin_amdgcn_mfma_f32_16x16x32_bf16(k1, qf1, sacc[st], 0, 0, 0);
    }
    // maxless softmax p = exp2(s*cs); mask only in the (single) tail block.
    // P row q=wm+lm, k-run st*16+quad*4..+3 -> one b64 write per st.
    bool full = (s0 + 64 <= T_);
#pragma unroll
    for (int st = 0; st < 4; st++) {
      float p0, p1, p2, p3;
      if (full) {
        p0 = exp2f(sacc[st][0] * cs);
        p1 = exp2f(sacc[st][1] * cs);
        p2 = exp2f(sacc[st][2] * cs);
        p3 = exp2f(sacc[st][3] * cs);
      } else {
        int kb = s0 + st * 16 + quad * 4;
        p0 = exp2f((kb + 0 < T_) ? sacc[st][0] * cs : -10000.f);
        p1 = exp2f((kb + 1 < T_) ? sacc[st][1] * cs : -10000.f);
        p2 = exp2f((kb + 2 < T_) ? sacc[st][2] * cs : -10000.f);
        p3 = exp2f((kb + 3 < T_) ? sacc[st][3] * cs : -10000.f);
      }
      lsum += (p0 + p1) + (p2 + p3);
      unsigned int w0, w1;
      asm("v_cvt_pk_bf16_f32 %0, %1, %2" : "=v"(w0) : "v"(p0), "v"(p1));
      asm("v_cvt_pk_bf16_f32 %0, %1, %2" : "=v"(w1) : "v"(p2), "v"(p3));
      *(uint2*)&Ps[(wm + lm) * 72 + st * 16 + quad * 4] = make_uint2(w0, w1);
    }
    // O += P V (same-wave produce/consume, no barrier)
#pragma unroll
    for (int ks = 0; ks < 2; ks++) {
      bf16x8 pf = *(const bf16x8*)&Ps[(wm + lm) * 72 + ks * 32 + quad * 8];
#pragma unroll
      for (int dt = 0; dt < 4; dt++) {
        bf16x8 vf = *(const bf16x8*)&Vt[(dt * 16 + lm) * 72 + ks * 32 + quad * 8];
        o_acc[dt] = __builtin_amdgcn_mfma_f32_16x16x32_bf16(pf, vf, o_acc[dt], 0, 0, 0);
      }
    }
  }

  // epilogue: lsum currently holds this lane's partial for column q=lm
  // (its 16 of 64 k-values). Reduce across quads, then redistribute 1/sum
  // into C-layout rows (q = quad*4+r) via width-16 shfl.
  lsum += __shfl_xor(lsum, 16, 64);
  lsum += __shfl_xor(lsum, 32, 64);
  float invq = 1.0f / lsum;
  float inv[4];
#pragma unroll
  for (int r = 0; r < 4; r++) inv[r] = __shfl(invq, quad * 4 + r, 16);
#pragma unroll
  for (int dt = 0; dt < 4; dt++)
#pragma unroll
    for (int r = 0; r < 4; r++)
      Ps[(wm + quad * 4 + r) * 72 + dt * 16 + lm] = f2bf(o_acc[dt][r] * inv[r]);
  {
    int rr = wm + (lane >> 2);
    int db = (lane & 3) * 16;
    int t = t0 + rr;
    if (t < T_) {
      bf16x8 a = *(const bf16x8*)&Ps[rr * 72 + db];
      bf16x8 b8 = *(const bf16x8*)&Ps[rr * 72 + db + 8];
      u16* op = o + ((size_t)(t * B_ + b)) * 512 + hh * 64 + db;
      *(bf16x8*)op = a;
      *(bf16x8*)(op + 8) = b8;
    }
  }
}

// ---------------------------------------------------------------------------
extern "C" void kernel_launch(void* const* d_in, const int* in_sizes, int n_in,
                              void* d_out, int out_size, void* d_ws, size_t ws_size,
                              hipStream_t stream) {
  const float* x       = (const float*)d_in[0];
  const int*   tsteps  = (const int*)  d_in[1];
  const float* se      = (const float*)d_in[2];
  const float* W_lmk   = (const float*)d_in[3];
  const float* b_lmk   = (const float*)d_in[4];
  const float* g_lmk   = (const float*)d_in[5];
  const float* be_lmk  = (const float*)d_in[6];
  const float* W_in    = (const float*)d_in[7];
  const float* b_in    = (const float*)d_in[8];
  const float* g_in    = (const float*)d_in[9];
  const float* be_in   = (const float*)d_in[10];
  const float* W_merge = (const float*)d_in[11];
  const float* b_merge = (const float*)d_in[12];
  const float* Wt1     = (const float*)d_in[13];
  const float* bt1     = (const float*)d_in[14];
  const float* Wt2     = (const float*)d_in[15];
  const float* bt2     = (const float*)d_in[16];
  const float* in_proj_w  = (const float*)d_in[17];
  const float* in_proj_b  = (const float*)d_in[18];
  const float* out_proj_w = (const float*)d_in[19];
  const float* out_proj_b = (const float*)d_in[20];
  const float* ln1_g   = (const float*)d_in[21];
  const float* ln1_b   = (const float*)d_in[22];
  const float* ln2_g   = (const float*)d_in[23];
  const float* ln2_b   = (const float*)d_in[24];
  const float* W_ff1   = (const float*)d_in[25];
  const float* b_ff1   = (const float*)d_in[26];
  const float* W_ff2   = (const float*)d_in[27];
  const float* b_ff2   = (const float*)d_in[28];
  const float* W_pose  = (const float*)d_in[29];
  const float* b_pose  = (const float*)d_in[30];
  const float* W_expr  = (const float*)d_in[31];
  const float* b_expr  = (const float*)d_in[32];
  float* out = (float*)d_out;

  // ---- workspace layout (~149 MB) ----
  float* pe      = (float*)d_ws;                          // 1024*512 f32
  u16*   h_bf    = (u16*)(pe + (size_t)PE_ROWS * 512);    // TB*512 bf16
  u16*   big_bf  = h_bf + (size_t)TB_ * 512;              // TB*2048 bf16
  u16*   bufO_bf = big_bf + (size_t)TB_ * 2048;           // TB*512 bf16
  u16*   bufP_bf = bufO_bf + (size_t)TB_ * 512;           // TB*512 bf16
  u16* merge_t = bufP_bf + (size_t)TB_ * 512;             // 512*1024
  u16* ip_t    = merge_t + (size_t)512 * 1024;            // L*1536*512
  u16* op_t    = ip_t    + (size_t)L_ * 1536 * 512;       // L*512*512
  u16* ff1_t   = op_t    + (size_t)L_ * 512 * 512;        // L*2048*512
  u16* ff2_t   = ff1_t   + (size_t)L_ * 2048 * 512;       // L*512*2048
  u16* lmk_t   = ff2_t   + (size_t)L_ * 512 * 2048;       // 512*256
  u16* xin_t   = lmk_t   + (size_t)512 * 256;             // 512*128
  u16* head_t  = xin_t   + (size_t)512 * 128;             // 128*512
  u16* wt1_t   = head_t  + (size_t)128 * 512;             // 512*512
  u16* wt2_t   = wt1_t   + (size_t)512 * 512;             // 512*512
  u16* ts_in   = wt2_t   + (size_t)512 * 512;             // 32*512
  u16* ts_mid  = ts_in   + (size_t)32 * 512;              // 32*512
  float* head_b = (float*)(ts_mid + (size_t)32 * 512);    // 128 f32
  // embed-phase aliases
  u16* seT_bf = bufO_bf;                                  // SB*256 bf16 (8.4<=16.8)
  u16* xT_bf  = bufP_bf;                                  // SB*128 bf16 (4.2<=16.8)
  u16* lmk_bf = big_bf;                                   // SB*512
  u16* xi_bf  = big_bf + (size_t)SB_ * 512;               // SB*512
  u16* cat_bf = big_bf + (size_t)SB_ * 1024;              // SB*1024 (fits in big)

  auto g128 = [&](const u16* A, const u16* Bt, const float* bias, u16* Cb,
                  int M, int N, int K, int flags) {
    dim3 grid(N / 128, (M + 127) / 128);
    gemm_bf16_t<128, 128, 32, 64><<<grid, 512, 0, stream>>>(A, Bt, bias, Cb, nullptr, M, N, K, flags);
  };
  auto g64 = [&](const u16* A, const u16* Bt, const float* bias, u16* Cb, float* Cf,
                 int M, int N, int K, int flags) {
    dim3 grid(N / 128, (M + 63) / 64);
    gemm_bf16_t<64, 128, 32, 32><<<grid, 512, 0, stream>>>(A, Bt, bias, Cb, Cf, M, N, K, flags);
  };

  // ---- weight prep ----
  wtrans_kernel<<<dim3(512 / 32, 1024 / 32, 1), 256, 0, stream>>>(
      W_merge, merge_t, 1024, 512, 0, 0);
  wtrans_kernel<<<dim3(1536 / 32, 512 / 32, L_), 256, 0, stream>>>(
      in_proj_w, ip_t, 512, 1536, (long)512 * 1536, (long)1536 * 512);
  wtrans_kernel<<<dim3(512 / 32, 512 / 32, L_), 256, 0, stream>>>(
      out_proj_w, op_t, 512, 512, (long)512 * 512, (long)512 * 512);
  wtrans_kernel<<<dim3(2048 / 32, 512 / 32, L_), 256, 0, stream>>>(
      W_ff1, ff1_t, 512, 2048, (long)512 * 2048, (long)2048 * 512);
  wtrans_kernel<<<dim3(512 / 32, 2048 / 32, L_), 256, 0, stream>>>(
      W_ff2, ff2_t, 2048, 512, (long)2048 * 512, (long)512 * 2048);
  wtrans_kernel<<<dim3(512 / 32, 512 / 32, 1), 256, 0, stream>>>(Wt1, wt1_t, 512, 512, 0, 0);
  wtrans_kernel<<<dim3(512 / 32, 512 / 32, 1), 256, 0, stream>>>(Wt2, wt2_t, 512, 512, 0, 0);
  wtrans_pad_kernel<<<dim3(512 / 32, 256 / 32), 256, 0, stream>>>(W_lmk, lmk_t, SD_, 256, 512);
  wtrans_pad_kernel<<<dim3(512 / 32, 128 / 32), 256, 0, stream>>>(W_in, xin_t, NF_, 128, 512);
  head_prep_kernel<<<(128 * 512) / 256, 256, 0, stream>>>(W_pose, b_pose, W_expr, b_expr,
                                                          head_t, head_b);

  // ---- embeddings ----
  pe_kernel<<<PE_ROWS, 256, 0, stream>>>(pe);
  transpose_sb_bf<<<(SB_ * 256 + 255) / 256, 256, 0, stream>>>(se, seT_bf, SD_, 256, SB_ * 256);
  transpose_sb_bf<<<(SB_ * 128 + 255) / 256, 256, 0, stream>>>(x, xT_bf, NF_, 128, SB_ * 128);
  g128(seT_bf, lmk_t, b_lmk, lmk_bf, SB_, 512, 256, 0);
  g128(xT_bf, xin_t, b_in, xi_bf, SB_, 512, 128, 0);
  ln_leaky_concat_kernel<<<SB_ * 2 / 4, 256, 0, stream>>>(lmk_bf, xi_bf, g_lmk, be_lmk,
                                                          g_in, be_in, cat_bf);
  g128(cat_bf, merge_t, b_merge, h_bf + (size_t)B_ * 512, SB_, 512, 1024, 0);
  // timestep MLP via MFMA: gather -> GEMM+silu -> GEMM (writes h rows 0..B)
  ts_gather_kernel<<<(32 * 512) / 256, 256, 0, stream>>>(tsteps, pe, ts_in);
  g64(ts_in, wt1_t, bt1, ts_mid, nullptr, 32, 512, 512, 2);
  g64(ts_mid, wt2_t, bt2, h_bf, nullptr, 32, 512, 512, 0);
  add_pe_kernel<<<TB_ * 512 / 8 / 256, 256, 0, stream>>>(h_bf, pe);

  // ---- transformer layers ----
  for (int l = 0; l < L_; l++) {
    g128(h_bf, ip_t + (size_t)l * 1536 * 512, in_proj_b + l * 1536,
         big_bf, TB_, 1536, 512, 0);
    attn_kernel<<<dim3(5, B_ * H_), 512, 0, stream>>>(big_bf, bufO_bf);
    g128(bufO_bf, op_t + (size_t)l * 512 * 512, out_proj_b + l * 512,
         bufP_bf, TB_, 512, 512, 0);
    add_ln_kernel<<<TB_ / 4, 256, 0, stream>>>(h_bf, bufP_bf, ln1_g + l * 512, ln1_b + l * 512);
    g128(h_bf, ff1_t + (size_t)l * 2048 * 512, b_ff1 + l * 2048,
         big_bf, TB_, 2048, 512, 1);
    g128(big_bf, ff2_t + (size_t)l * 512 * 2048, b_ff2 + l * 512,
         bufP_bf, TB_, 512, 2048, 0);
    add_ln_kernel<<<TB_ / 4, 256, 0, stream>>>(h_bf, bufP_bf, ln2_g + l * 512, ln2_b + l * 512);
  }

  // ---- fused output heads: one GEMM, fp32 remap epilogue ----
  g64(h_bf + (size_t)B_ * 512, head_t, head_b, nullptr, out, SB_, 128, 512, 4);
}